// Round 3
// baseline (562.084 us; speedup 1.0000x reference)
//
#include <hip/hip_runtime.h>
#include <stdint.h>

// WaveletSparsityPrior: 3-level Haar, loss = sum_lvl w_lvl * mean min(|c|, t_lvl)
// SINGLE fused dispatch (+ 516 B counter memset). R2 finding: measured time =
// ~154 us harness poison fills (2x 512 MiB at 86% HBM peak, uncontrollable) +
// ~37 us our kernels; pass_a is BW-bound at ~20 us floor (134 MB mandatory
// read), so the only attackable cost was pass_b's separate dispatch (launch +
// 128-wave latency-bound tail). This round folds pass_b into pass_a's tail:
//
//  fused (grid 16x128, 256 thr): pass_a body unchanged (wave-per-strip, all
//    lane-contiguous float4 loads, Haar in registers, 512-bin LDS hist,
//    plain-stored sub-hist). Then threadfence + per-batch completion counter
//    (memset-initialized): the 16th block of batch b runs the old pass_b scan
//    on wave 0 (overlapped with other batches' main work), stores loss_b/sig_b,
//    bumps a global done-counter; the 128th finalizer computes the final
//    128-element means and plain-stores out[0..1] (no d_out init dependence,
//    no same-address atomics, deterministic final sum).
//  Speculative t = 0.2 (clip top) -> exact loss because sigma~1.0 ->
//    2.5*sigma clips (verified absmax=0 across sessions). Correction
//    recompute only if t != 0.2 (never taken for this input).
//
// ws layout: f32 [0,2048) partials[b*16+sub]; u32 ghist[128*16*512] (4 MB);
//            u32 cnt[128]; u32 done[1]; f32 loss_arr[128]; f32 sig_arr[128].
// hipMemsetAsync zeroes cnt+done (516 B) before the kernel each iteration.

static constexpr int BATCH = 128;
static constexpr int W = 512;
static constexpr int NBIN = 512;      // bin width 1/256 over [0,2)

__device__ __forceinline__ float block_reduce_sum(float v, float* lds) {
    #pragma unroll
    for (int off = 32; off > 0; off >>= 1)
        v += __shfl_down(v, off, 64);
    const int lane = threadIdx.x & 63;
    const int wave = threadIdx.x >> 6;
    if (lane == 0) lds[wave] = v;
    __syncthreads();
    if (threadIdx.x == 0) {
        float s = 0.0f;
        for (int w = 0; w < 4; ++w) s += lds[w];
        lds[0] = s;
    }
    __syncthreads();
    const float r = lds[0];
    __syncthreads();
    return r;
}

__device__ __forceinline__ void haar_quad(float a, float b, float c, float d,
                                          float& cA, float& cH, float& cV, float& cD) {
    const float sab = a + b, scd = c + d, dab = a - b, dcd = c - d;
    cA = 0.5f * (sab + scd);
    cH = 0.5f * (sab - scd);
    cV = 0.5f * (dab + dcd);
    cD = 0.5f * (dab - dcd);
}

// Legacy per-thread 8x8 version (used only on the never-taken correction path).
__device__ __forceinline__ float wavelet_block_loss(
        const float* __restrict__ blk, float t1, float t2, float t3) {
    float cA1[4][4];
    float s1 = 0.0f, s2 = 0.0f, s3 = 0.0f;
    #pragma unroll
    for (int rr = 0; rr < 4; ++rr) {
        const float4 r0a = *(const float4*)(blk + (size_t)(2 * rr) * W);
        const float4 r0b = *(const float4*)(blk + (size_t)(2 * rr) * W + 4);
        const float4 r1a = *(const float4*)(blk + (size_t)(2 * rr + 1) * W);
        const float4 r1b = *(const float4*)(blk + (size_t)(2 * rr + 1) * W + 4);
        const float top[8] = {r0a.x, r0a.y, r0a.z, r0a.w, r0b.x, r0b.y, r0b.z, r0b.w};
        const float bot[8] = {r1a.x, r1a.y, r1a.z, r1a.w, r1b.x, r1b.y, r1b.z, r1b.w};
        #pragma unroll
        for (int cc = 0; cc < 4; ++cc) {
            float cA, cH, cV, cD;
            haar_quad(top[2*cc], top[2*cc+1], bot[2*cc], bot[2*cc+1], cA, cH, cV, cD);
            s1 += fminf(fabsf(cH), t1) + fminf(fabsf(cV), t1) + fminf(fabsf(cD), t1);
            cA1[rr][cc] = cA;
        }
    }
    float cA2[2][2];
    #pragma unroll
    for (int rr = 0; rr < 2; ++rr)
        #pragma unroll
        for (int cc = 0; cc < 2; ++cc) {
            float cA, cH, cV, cD;
            haar_quad(cA1[2*rr][2*cc], cA1[2*rr][2*cc+1],
                      cA1[2*rr+1][2*cc], cA1[2*rr+1][2*cc+1], cA, cH, cV, cD);
            s2 += fminf(fabsf(cH), t2) + fminf(fabsf(cV), t2) + fminf(fabsf(cD), t2);
            cA2[rr][cc] = cA;
        }
    {
        float cA, cH, cV, cD;
        haar_quad(cA2[0][0], cA2[0][1], cA2[1][0], cA2[1][1], cA, cH, cV, cD);
        s3 = fminf(fabsf(cH), t3) + fminf(fabsf(cV), t3) + fminf(fabsf(cD), t3);
    }
    const float w1 = 1.0f / (9.0f * 65536.0f);
    const float w2 = 1.0f / (6.0f * 16384.0f);
    const float w3 = 1.0f / (3.0f * 4096.0f);
    return s1 * w1 + s2 * w2 + s3 * w3;
}

__global__ __launch_bounds__(256) void fused(const float* __restrict__ x,
                                             float* __restrict__ partials,
                                             uint32_t* __restrict__ ghist,
                                             uint32_t* __restrict__ cnt,
                                             uint32_t* __restrict__ done,
                                             float* __restrict__ loss_arr,
                                             float* __restrict__ sig_arr,
                                             float* __restrict__ out) {
    __shared__ uint32_t h[NBIN];
    __shared__ float lds[8];
    __shared__ uint32_t flag;
    const int tid  = threadIdx.x;
    const int lane = tid & 63;
    const int wv   = tid >> 6;          // wave 0..3
    const int sub  = blockIdx.x;        // 0..15
    const int b    = blockIdx.y;        // 0..127

    h[tid] = 0u;
    h[tid + 256] = 0u;
    __syncthreads();

    const float BASE = 40.0f / 400.0f;
    const float t3 = BASE * 2.0f, t2 = t3 * 0.5f, t1 = t3 * 0.25f;

    // Wave strip: 8 rows x 512 cols. Strip index R = sub*4 + wv (0..63).
    const int R = sub * 4 + wv;
    const float* strip = x + (size_t)b * W * W + (size_t)(R * 8) * W;

    float cA1A[4][2], cA1B[4][2];       // [row-pair rp][in-lane level-1 col]
    float s1 = 0.0f, s2 = 0.0f, s3 = 0.0f;

    // Loads issued in batches of 8 float4 (two row-pairs) for MLP; compute
    // order (and fp32 accumulation order) unchanged -> bit-identical.
    #pragma unroll
    for (int half = 0; half < 2; ++half) {
        float4 ld[2][4];    // [rp within half][tA,bA,tB,bB]
        #pragma unroll
        for (int q = 0; q < 2; ++q) {
            const int rp = half * 2 + q;
            const float* r0 = strip + (size_t)(2 * rp) * W;
            const float* r1 = strip + (size_t)(2 * rp + 1) * W;
            // perfectly lane-contiguous: lane i -> byte offset 16*i
            ld[q][0] = *(const float4*)(r0 + 4 * lane);
            ld[q][1] = *(const float4*)(r1 + 4 * lane);
            ld[q][2] = *(const float4*)(r0 + 256 + 4 * lane);
            ld[q][3] = *(const float4*)(r1 + 256 + 4 * lane);
        }
        #pragma unroll
        for (int q = 0; q < 2; ++q) {
            const int rp = half * 2 + q;
            const float4 tA = ld[q][0], bA = ld[q][1];
            const float4 tB = ld[q][2], bB = ld[q][3];

            float cA, cH, cV, cD;
            haar_quad(tA.x, tA.y, bA.x, bA.y, cA, cH, cV, cD);
            s1 += fminf(fabsf(cH), t1) + fminf(fabsf(cV), t1) + fminf(fabsf(cD), t1);
            cA1A[rp][0] = cA;
            haar_quad(tA.z, tA.w, bA.z, bA.w, cA, cH, cV, cD);
            s1 += fminf(fabsf(cH), t1) + fminf(fabsf(cV), t1) + fminf(fabsf(cD), t1);
            cA1A[rp][1] = cA;
            haar_quad(tB.x, tB.y, bB.x, bB.y, cA, cH, cV, cD);
            s1 += fminf(fabsf(cH), t1) + fminf(fabsf(cV), t1) + fminf(fabsf(cD), t1);
            cA1B[rp][0] = cA;
            haar_quad(tB.z, tB.w, bB.z, bB.w, cA, cH, cV, cD);
            s1 += fminf(fabsf(cH), t1) + fminf(fabsf(cV), t1) + fminf(fabsf(cD), t1);
            cA1B[rp][1] = cA;
        }
    }

    float cA2A[2], cA2B[2];             // level-2 cA, rows 0..1, in-lane col
    #pragma unroll
    for (int j = 0; j < 2; ++j) {
        float cA, cH, cV, cD;
        haar_quad(cA1A[2*j][0], cA1A[2*j][1], cA1A[2*j+1][0], cA1A[2*j+1][1],
                  cA, cH, cV, cD);
        s2 += fminf(fabsf(cH), t2) + fminf(fabsf(cV), t2) + fminf(fabsf(cD), t2);
        cA2A[j] = cA;
        haar_quad(cA1B[2*j][0], cA1B[2*j][1], cA1B[2*j+1][0], cA1B[2*j+1][1],
                  cA, cH, cV, cD);
        s2 += fminf(fabsf(cH), t2) + fminf(fabsf(cV), t2) + fminf(fabsf(cD), t2);
        cA2B[j] = cA;
    }

    // level-3: cols pair across adjacent lanes (2k, 2k+1).
    // Even lane computes the A-half quad, odd lane the B-half quad.
    // haar_quad(b,a,d,c) only negates cV,cD vs haar_quad(a,b,c,d), and we
    // only consume |coeff|, so each lane can use (own, partner) order.
    {
        const float send0 = (lane & 1) ? cA2A[0] : cA2B[0];
        const float send1 = (lane & 1) ? cA2A[1] : cA2B[1];
        const float p0 = __shfl_xor(send0, 1, 64);
        const float p1 = __shfl_xor(send1, 1, 64);
        const float q0 = (lane & 1) ? cA2B[0] : cA2A[0];
        const float q2 = (lane & 1) ? cA2B[1] : cA2A[1];
        float cA, cH, cV, cD;
        haar_quad(q0, p0, q2, p1, cA, cH, cV, cD);
        const float aH = fabsf(cH), aV = fabsf(cV), aD = fabsf(cD);
        s3 += fminf(aH, t3) + fminf(aV, t3) + fminf(aD, t3);
        atomicAdd(&h[min((int)(aH * 256.0f), NBIN - 1)], 1u);
        atomicAdd(&h[min((int)(aV * 256.0f), NBIN - 1)], 1u);
        atomicAdd(&h[min((int)(aD * 256.0f), NBIN - 1)], 1u);
    }

    // level weights: 1/3·1/3/65536 (L1), 1/2·1/3/16384 (L2), 1/1·1/3/4096 (L3)
    const float w1 = 1.0f / (9.0f * 65536.0f);
    const float w2 = 1.0f / (6.0f * 16384.0f);
    const float w3 = 1.0f / (3.0f * 4096.0f);
    const float part = s1 * w1 + s2 * w2 + s3 * w3;

    const float tot = block_reduce_sum(part, lds);   // barriers fence h[] too
    if (tid == 0) partials[b * 16 + sub] = tot;

    // plain-store this block's complete sub-histogram (no memset needed)
    uint32_t* gh = ghist + ((size_t)b * 16 + sub) * NBIN;
    gh[tid] = h[tid];
    gh[tid + 256] = h[tid + 256];

    // ---- completion protocol (threadFenceReduction pattern) ----
    // Every thread fences its own stores, barrier, then thread 0 bumps the
    // per-batch counter. The 16th arriver finalizes the batch.
    __threadfence();
    __syncthreads();
    if (tid == 0)
        flag = (atomicAdd(&cnt[b], 1u) == 15u) ? 1u : 0u;
    __syncthreads();
    if (flag == 0u) return;

    // ---- batch finalizer: old pass_b body on wave 0 ----
    if (tid >= 64) return;
    __threadfence();                      // acquire: see other blocks' stores
    {
        const int ln = tid;               // 0..63; owns bins [8*ln, 8*ln+8)

        // Hoist partials load so its latency overlaps the histogram burst.
        const float pval = (ln < 16) ? partials[b * 16 + ln] : 0.0f;

        uint32_t c[8] = {0, 0, 0, 0, 0, 0, 0, 0};
        #pragma unroll
        for (int s = 0; s < 16; ++s) {
            const uint32_t* hb = ghist + ((size_t)b * 16 + s) * NBIN + ln * 8;
            const uint4 u0 = *(const uint4*)(hb);
            const uint4 u1 = *(const uint4*)(hb + 4);
            c[0] += u0.x; c[1] += u0.y; c[2] += u0.z; c[3] += u0.w;
            c[4] += u1.x; c[5] += u1.y; c[6] += u1.z; c[7] += u1.w;
        }

        uint32_t lane_sum = 0;
        #pragma unroll
        for (int j = 0; j < 8; ++j) lane_sum += c[j];

        // exclusive prefix of lane_sum across the wave
        uint32_t incl = lane_sum;
        #pragma unroll
        for (int off = 1; off < 64; off <<= 1) {
            const uint32_t v = __shfl_up(incl, off, 64);
            if (ln >= off) incl += v;
        }
        uint32_t run = incl - lane_sum;

        int bin1 = 0x7FFFFFFF, bin2 = 0x7FFFFFFF;
        #pragma unroll
        for (int j = 0; j < 8; ++j) {
            const uint32_t nxt = run + c[j];
            if (run < 6144u && nxt >= 6144u) bin1 = ln * 8 + j;
            if (run < 6145u && nxt >= 6145u) bin2 = ln * 8 + j;
            run = nxt;
        }
        #pragma unroll
        for (int off = 32; off > 0; off >>= 1) {
            bin1 = min(bin1, __shfl_down(bin1, off, 64));
            bin2 = min(bin2, __shfl_down(bin2, off, 64));
        }
        bin1 = __shfl(bin1, 0, 64);
        bin2 = __shfl(bin2, 0, 64);

        const float v1 = ((float)bin1 + 0.5f) * (1.0f / 256.0f);
        const float v2 = ((float)bin2 + 0.5f) * (1.0f / 256.0f);
        const float med = 0.5f * (v1 + v2);          // err <= 1/512 ~ 2e-3
        const float sig = med * (float)(1.0 / 0.6745);
        const float TTOP = BASE * 2.0f;
        const float t = fminf(fmaxf(sig * 2.5f, BASE * 0.5f), TTOP);

        float loss_b;
        if (t == TTOP) {
            float v = pval;
            #pragma unroll
            for (int off = 32; off > 0; off >>= 1) v += __shfl_down(v, off, 64);
            loss_b = v;
        } else {
            // correction: recompute this batch with true thresholds (rare)
            float prt = 0.0f;
            #pragma unroll 1
            for (int k = 0; k < 64; ++k) {
                const int p = k * 64 + ln;
                const int i3 = p >> 6, j3 = p & 63;
                const float* blk = x + (size_t)b * W * W + (size_t)(i3 * 8) * W + j3 * 8;
                prt += wavelet_block_loss(blk, t * 0.25f, t * 0.5f, t);
            }
            #pragma unroll
            for (int off = 32; off > 0; off >>= 1) prt += __shfl_down(prt, off, 64);
            loss_b = prt;
        }

        // publish batch result; 128th finalizer computes the global means
        uint32_t dold = 0u;
        if (ln == 0) {
            loss_arr[b] = loss_b;
            sig_arr[b]  = sig;
            __threadfence();
            dold = atomicAdd(done, 1u);
        }
        dold = (uint32_t)__shfl((int)dold, 0, 64);
        if (dold == (uint32_t)(BATCH - 1)) {
            __threadfence();              // acquire: see all loss/sig stores
            float va = loss_arr[ln] + loss_arr[ln + 64];
            float vs = sig_arr[ln]  + sig_arr[ln + 64];
            #pragma unroll
            for (int off = 32; off > 0; off >>= 1) {
                va += __shfl_down(va, off, 64);
                vs += __shfl_down(vs, off, 64);
            }
            if (ln == 0) {
                out[0] = va * (1.0f / (float)BATCH);
                out[1] = vs * (1.0f / (float)BATCH);
            }
        }
    }
}

extern "C" void kernel_launch(void* const* d_in, const int* in_sizes, int n_in,
                              void* d_out, int out_size, void* d_ws, size_t ws_size,
                              hipStream_t stream) {
    const float* x = (const float*)d_in[0];
    float* ws = (float*)d_ws;
    float* partials = ws;                                  // 2048 floats
    uint32_t* ghist = (uint32_t*)(ws + 2048);              // 128*16*512 u32 = 4 MB
    uint32_t* cnt   = ghist + (size_t)BATCH * 16 * NBIN;   // 128 u32
    uint32_t* done  = cnt + BATCH;                         // 1 u32
    float* loss_arr = (float*)(done + 1);                  // 128 f32
    float* sig_arr  = loss_arr + BATCH;                    // 128 f32

    // zero the completion counters (516 B; graph-capturable, stream-ordered)
    hipMemsetAsync(cnt, 0, (BATCH + 1) * sizeof(uint32_t), stream);

    dim3 grid(16, BATCH);
    fused<<<grid, 256, 0, stream>>>(x, partials, ghist, cnt, done,
                                    loss_arr, sig_arr, (float*)d_out);
}

// Round 4
// 190.988 us; speedup vs baseline: 2.9430x; 2.9430x over previous
//
#include <hip/hip_runtime.h>
#include <stdint.h>

// WaveletSparsityPrior: 3-level Haar, loss = sum_lvl w_lvl * mean min(|c|, t_lvl)
// TWO dispatches: pass_a -> pass_b. R3 lesson: fusing them via threadfence +
// completion counters cost 440 us (VALUBusy 1.3%) -- device-scope fences from
// 2048 blocks serialize on cross-XCD L2 writebacks. The kernel boundary gives
// that coherence once, for free. Structure reverted to the 191-us R2 version;
// this round's delta: ghist packed as u16 pairs (max count/block = 768 <<
// 65535, bit-exact), halving hist store+fetch traffic.
//
//  pass_a (grid 16x128, 256 thr): each WAVE owns an 8-row x 512-col strip.
//    Lane-contiguous float4 loads (lane i -> byte 16*i), batched 8-deep for
//    MLP; Haar tree in registers: level-1/2 in-lane, level-3 via shfl_xor(1)
//    with even-lane=A-half / odd-lane=B-half split (|coeff| invariant under
//    column swap -> all 64 lanes active). 512-bin LDS histogram of |level-3
//    details|, plain-stored PACKED (2x u16 per u32) to ghist[b][sub][256]
//    (overwrites poison -> no memset). Block (0,0) zeroes d_out.
//    Speculative t = 0.2 (clip top) -> exact loss because sigma~1.0 ->
//    2.5*sigma clips (verified absmax=0 across all passing rounds).
//  pass_b (128 blocks x 64): sum 16 packed sub-hists (1 uint4/lane each,
//    fully unrolled -- latency-bound at 0.5 wave/CU), scan for order stats
//    6143/6144 -> sigma (bin-midpoint err <= 2e-3 << 2e-2 threshold) -> t ->
//    finalize via 2 fp32 atomicAdds. Correction recompute only if t != 0.2
//    (never taken for this input).
//
// ws layout: f32 [0,2048) partials[b*16+sub]; u32 [2048, +128*16*256) ghist.

static constexpr int BATCH = 128;
static constexpr int W = 512;
static constexpr int NBIN = 512;      // bin width 1/256 over [0,2)
static constexpr int NPACK = NBIN / 2;   // packed u32 words per sub-hist

__device__ __forceinline__ float block_reduce_sum(float v, float* lds) {
    #pragma unroll
    for (int off = 32; off > 0; off >>= 1)
        v += __shfl_down(v, off, 64);
    const int lane = threadIdx.x & 63;
    const int wave = threadIdx.x >> 6;
    if (lane == 0) lds[wave] = v;
    __syncthreads();
    if (threadIdx.x == 0) {
        float s = 0.0f;
        for (int w = 0; w < 4; ++w) s += lds[w];
        lds[0] = s;
    }
    __syncthreads();
    const float r = lds[0];
    __syncthreads();
    return r;
}

__device__ __forceinline__ void haar_quad(float a, float b, float c, float d,
                                          float& cA, float& cH, float& cV, float& cD) {
    const float sab = a + b, scd = c + d, dab = a - b, dcd = c - d;
    cA = 0.5f * (sab + scd);
    cH = 0.5f * (sab - scd);
    cV = 0.5f * (dab + dcd);
    cD = 0.5f * (dab - dcd);
}

// Legacy per-thread 8x8 version (used only on the never-taken correction path).
__device__ __forceinline__ float wavelet_block_loss(
        const float* __restrict__ blk, float t1, float t2, float t3) {
    float cA1[4][4];
    float s1 = 0.0f, s2 = 0.0f, s3 = 0.0f;
    #pragma unroll
    for (int rr = 0; rr < 4; ++rr) {
        const float4 r0a = *(const float4*)(blk + (size_t)(2 * rr) * W);
        const float4 r0b = *(const float4*)(blk + (size_t)(2 * rr) * W + 4);
        const float4 r1a = *(const float4*)(blk + (size_t)(2 * rr + 1) * W);
        const float4 r1b = *(const float4*)(blk + (size_t)(2 * rr + 1) * W + 4);
        const float top[8] = {r0a.x, r0a.y, r0a.z, r0a.w, r0b.x, r0b.y, r0b.z, r0b.w};
        const float bot[8] = {r1a.x, r1a.y, r1a.z, r1a.w, r1b.x, r1b.y, r1b.z, r1b.w};
        #pragma unroll
        for (int cc = 0; cc < 4; ++cc) {
            float cA, cH, cV, cD;
            haar_quad(top[2*cc], top[2*cc+1], bot[2*cc], bot[2*cc+1], cA, cH, cV, cD);
            s1 += fminf(fabsf(cH), t1) + fminf(fabsf(cV), t1) + fminf(fabsf(cD), t1);
            cA1[rr][cc] = cA;
        }
    }
    float cA2[2][2];
    #pragma unroll
    for (int rr = 0; rr < 2; ++rr)
        #pragma unroll
        for (int cc = 0; cc < 2; ++cc) {
            float cA, cH, cV, cD;
            haar_quad(cA1[2*rr][2*cc], cA1[2*rr][2*cc+1],
                      cA1[2*rr+1][2*cc], cA1[2*rr+1][2*cc+1], cA, cH, cV, cD);
            s2 += fminf(fabsf(cH), t2) + fminf(fabsf(cV), t2) + fminf(fabsf(cD), t2);
            cA2[rr][cc] = cA;
        }
    {
        float cA, cH, cV, cD;
        haar_quad(cA2[0][0], cA2[0][1], cA2[1][0], cA2[1][1], cA, cH, cV, cD);
        s3 = fminf(fabsf(cH), t3) + fminf(fabsf(cV), t3) + fminf(fabsf(cD), t3);
    }
    const float w1 = 1.0f / (9.0f * 65536.0f);
    const float w2 = 1.0f / (6.0f * 16384.0f);
    const float w3 = 1.0f / (3.0f * 4096.0f);
    return s1 * w1 + s2 * w2 + s3 * w3;
}

__global__ __launch_bounds__(256) void pass_a(const float* __restrict__ x,
                                              float* __restrict__ partials,
                                              uint32_t* __restrict__ ghist,
                                              float* __restrict__ out) {
    __shared__ uint32_t h[NBIN];
    __shared__ float lds[8];
    const int tid  = threadIdx.x;
    const int lane = tid & 63;
    const int wv   = tid >> 6;          // wave 0..3
    const int sub  = blockIdx.x;        // 0..15
    const int b    = blockIdx.y;        // 0..127

    h[tid] = 0u;
    h[tid + 256] = 0u;
    if (sub == 0 && b == 0 && tid < 2) out[tid] = 0.0f;   // init d_out
    __syncthreads();

    const float BASE = 40.0f / 400.0f;
    const float t3 = BASE * 2.0f, t2 = t3 * 0.5f, t1 = t3 * 0.25f;

    // Wave strip: 8 rows x 512 cols. Strip index R = sub*4 + wv (0..63).
    const int R = sub * 4 + wv;
    const float* strip = x + (size_t)b * W * W + (size_t)(R * 8) * W;

    float cA1A[4][2], cA1B[4][2];       // [row-pair rp][in-lane level-1 col]
    float s1 = 0.0f, s2 = 0.0f, s3 = 0.0f;

    // Loads issued in batches of 8 float4 (two row-pairs) for MLP; compute
    // order (and fp32 accumulation order) unchanged -> bit-identical.
    #pragma unroll
    for (int half = 0; half < 2; ++half) {
        float4 ld[2][4];    // [rp within half][tA,bA,tB,bB]
        #pragma unroll
        for (int q = 0; q < 2; ++q) {
            const int rp = half * 2 + q;
            const float* r0 = strip + (size_t)(2 * rp) * W;
            const float* r1 = strip + (size_t)(2 * rp + 1) * W;
            // perfectly lane-contiguous: lane i -> byte offset 16*i
            ld[q][0] = *(const float4*)(r0 + 4 * lane);
            ld[q][1] = *(const float4*)(r1 + 4 * lane);
            ld[q][2] = *(const float4*)(r0 + 256 + 4 * lane);
            ld[q][3] = *(const float4*)(r1 + 256 + 4 * lane);
        }
        #pragma unroll
        for (int q = 0; q < 2; ++q) {
            const int rp = half * 2 + q;
            const float4 tA = ld[q][0], bA = ld[q][1];
            const float4 tB = ld[q][2], bB = ld[q][3];

            float cA, cH, cV, cD;
            haar_quad(tA.x, tA.y, bA.x, bA.y, cA, cH, cV, cD);
            s1 += fminf(fabsf(cH), t1) + fminf(fabsf(cV), t1) + fminf(fabsf(cD), t1);
            cA1A[rp][0] = cA;
            haar_quad(tA.z, tA.w, bA.z, bA.w, cA, cH, cV, cD);
            s1 += fminf(fabsf(cH), t1) + fminf(fabsf(cV), t1) + fminf(fabsf(cD), t1);
            cA1A[rp][1] = cA;
            haar_quad(tB.x, tB.y, bB.x, bB.y, cA, cH, cV, cD);
            s1 += fminf(fabsf(cH), t1) + fminf(fabsf(cV), t1) + fminf(fabsf(cD), t1);
            cA1B[rp][0] = cA;
            haar_quad(tB.z, tB.w, bB.z, bB.w, cA, cH, cV, cD);
            s1 += fminf(fabsf(cH), t1) + fminf(fabsf(cV), t1) + fminf(fabsf(cD), t1);
            cA1B[rp][1] = cA;
        }
    }

    float cA2A[2], cA2B[2];             // level-2 cA, rows 0..1, in-lane col
    #pragma unroll
    for (int j = 0; j < 2; ++j) {
        float cA, cH, cV, cD;
        haar_quad(cA1A[2*j][0], cA1A[2*j][1], cA1A[2*j+1][0], cA1A[2*j+1][1],
                  cA, cH, cV, cD);
        s2 += fminf(fabsf(cH), t2) + fminf(fabsf(cV), t2) + fminf(fabsf(cD), t2);
        cA2A[j] = cA;
        haar_quad(cA1B[2*j][0], cA1B[2*j][1], cA1B[2*j+1][0], cA1B[2*j+1][1],
                  cA, cH, cV, cD);
        s2 += fminf(fabsf(cH), t2) + fminf(fabsf(cV), t2) + fminf(fabsf(cD), t2);
        cA2B[j] = cA;
    }

    // level-3: cols pair across adjacent lanes (2k, 2k+1).
    // Even lane computes the A-half quad, odd lane the B-half quad.
    // haar_quad(b,a,d,c) only negates cV,cD vs haar_quad(a,b,c,d), and we
    // only consume |coeff|, so each lane can use (own, partner) order.
    {
        const float send0 = (lane & 1) ? cA2A[0] : cA2B[0];
        const float send1 = (lane & 1) ? cA2A[1] : cA2B[1];
        const float p0 = __shfl_xor(send0, 1, 64);
        const float p1 = __shfl_xor(send1, 1, 64);
        const float q0 = (lane & 1) ? cA2B[0] : cA2A[0];
        const float q2 = (lane & 1) ? cA2B[1] : cA2A[1];
        float cA, cH, cV, cD;
        haar_quad(q0, p0, q2, p1, cA, cH, cV, cD);
        const float aH = fabsf(cH), aV = fabsf(cV), aD = fabsf(cD);
        s3 += fminf(aH, t3) + fminf(aV, t3) + fminf(aD, t3);
        atomicAdd(&h[min((int)(aH * 256.0f), NBIN - 1)], 1u);
        atomicAdd(&h[min((int)(aV * 256.0f), NBIN - 1)], 1u);
        atomicAdd(&h[min((int)(aD * 256.0f), NBIN - 1)], 1u);
    }

    // level weights: 1/3·1/3/65536 (L1), 1/2·1/3/16384 (L2), 1/1·1/3/4096 (L3)
    const float w1 = 1.0f / (9.0f * 65536.0f);
    const float w2 = 1.0f / (6.0f * 16384.0f);
    const float w3 = 1.0f / (3.0f * 4096.0f);
    const float part = s1 * w1 + s2 * w2 + s3 * w3;

    const float tot = block_reduce_sum(part, lds);   // barriers fence h[] too
    if (tid == 0) partials[b * 16 + sub] = tot;

    // plain-store this block's sub-histogram PACKED: word tid = bins
    // (2*tid, 2*tid+1) as lo/hi u16 (max count/block = 768, no overflow).
    uint32_t* gh = ghist + ((size_t)b * 16 + sub) * NPACK;
    gh[tid] = (h[2 * tid] & 0xFFFFu) | (h[2 * tid + 1] << 16);
}

// One wave per batch: sum 16 packed sub-hists, scan for order stats
// 6143/6144, sigma from bin midpoint, finalize loss.
__global__ __launch_bounds__(64) void pass_b(const uint32_t* __restrict__ ghist,
                                             const float* __restrict__ partials,
                                             const float* __restrict__ x,
                                             float* __restrict__ out) {
    const int b = blockIdx.x;
    const int lane = threadIdx.x;   // 0..63; owns bins [8*lane, 8*lane+8)
                                    //        = packed words [4*lane, 4*lane+4)

    // Hoist the partials load so its latency overlaps the histogram burst.
    const float pval = (lane < 16) ? partials[b * 16 + lane] : 0.0f;

    uint32_t c[8] = {0, 0, 0, 0, 0, 0, 0, 0};

    // Fully unrolled: latency-bound (128 waves grid-wide); one uint4 per
    // sub-hist -> 16 loads in flight.
    #pragma unroll
    for (int s = 0; s < 16; ++s) {
        const uint32_t* hb = ghist + ((size_t)b * 16 + s) * (NBIN / 2) + lane * 4;
        const uint4 u = *(const uint4*)(hb);
        c[0] += u.x & 0xFFFFu; c[1] += u.x >> 16;
        c[2] += u.y & 0xFFFFu; c[3] += u.y >> 16;
        c[4] += u.z & 0xFFFFu; c[5] += u.z >> 16;
        c[6] += u.w & 0xFFFFu; c[7] += u.w >> 16;
    }

    uint32_t lane_sum = 0;
    #pragma unroll
    for (int j = 0; j < 8; ++j) lane_sum += c[j];

    // exclusive prefix of lane_sum across the wave
    uint32_t incl = lane_sum;
    #pragma unroll
    for (int off = 1; off < 64; off <<= 1) {
        const uint32_t v = __shfl_up(incl, off, 64);
        if (lane >= off) incl += v;
    }
    uint32_t run = incl - lane_sum;

    int bin1 = 0x7FFFFFFF, bin2 = 0x7FFFFFFF;
    #pragma unroll
    for (int j = 0; j < 8; ++j) {
        const uint32_t nxt = run + c[j];
        if (run < 6144u && nxt >= 6144u) bin1 = lane * 8 + j;
        if (run < 6145u && nxt >= 6145u) bin2 = lane * 8 + j;
        run = nxt;
    }
    #pragma unroll
    for (int off = 32; off > 0; off >>= 1) {
        bin1 = min(bin1, __shfl_down(bin1, off, 64));
        bin2 = min(bin2, __shfl_down(bin2, off, 64));
    }
    bin1 = __shfl(bin1, 0, 64);
    bin2 = __shfl(bin2, 0, 64);

    const float v1 = ((float)bin1 + 0.5f) * (1.0f / 256.0f);
    const float v2 = ((float)bin2 + 0.5f) * (1.0f / 256.0f);
    const float med = 0.5f * (v1 + v2);          // err <= 1/512 ~ 2e-3
    const float sig = med * (float)(1.0 / 0.6745);
    const float BASE = 40.0f / 400.0f;
    const float TTOP = BASE * 2.0f;
    const float t = fminf(fmaxf(sig * 2.5f, BASE * 0.5f), TTOP);

    float loss_b;
    if (t == TTOP) {
        float v = pval;
        #pragma unroll
        for (int off = 32; off > 0; off >>= 1) v += __shfl_down(v, off, 64);
        loss_b = v;
    } else {
        // correction: recompute this batch with the true thresholds (rare)
        float part = 0.0f;
        #pragma unroll 1
        for (int k = 0; k < 64; ++k) {
            const int p = k * 64 + lane;
            const int i3 = p >> 6, j3 = p & 63;
            const float* blk = x + (size_t)b * W * W + (size_t)(i3 * 8) * W + j3 * 8;
            part += wavelet_block_loss(blk, t * 0.25f, t * 0.5f, t);
        }
        #pragma unroll
        for (int off = 32; off > 0; off >>= 1) part += __shfl_down(part, off, 64);
        loss_b = part;
    }

    if (lane == 0) {
        atomicAdd(&out[0], loss_b * (1.0f / (float)BATCH));
        atomicAdd(&out[1], sig * (1.0f / (float)BATCH));
    }
}

extern "C" void kernel_launch(void* const* d_in, const int* in_sizes, int n_in,
                              void* d_out, int out_size, void* d_ws, size_t ws_size,
                              hipStream_t stream) {
    const float* x = (const float*)d_in[0];
    float* ws = (float*)d_ws;
    float* partials = ws;                          // 2048 floats
    uint32_t* ghist = (uint32_t*)(ws + 2048);      // 128*16*256 u32 = 2 MB (packed u16 pairs)

    dim3 grid(16, BATCH);
    pass_a<<<grid, 256, 0, stream>>>(x, partials, ghist, (float*)d_out);
    pass_b<<<BATCH, 64, 0, stream>>>(ghist, partials, x, (float*)d_out);
}